// Round 5
// baseline (288.901 us; speedup 1.0000x reference)
//
#include <hip/hip_runtime.h>

#define NS 32768
#define NC 395
#define FD 512
#define W  32                  // dims per slice
#define NSLICE (FD / W)        // 16
#define S  8                   // sample splits
#define CHUNK (NS / S)         // 4096 samples scanned per block
#define TPB 512

// Static device scratch — every slot rewritten each call.
// g_partial[b][NC*W], b = (slice<<4)|(mod<<3)|split   (~12.9 MB)
__device__ float g_partial[NSLICE * 2 * S * NC * W];
__device__ int   g_pcount[S * NC];

// ---------------------------------------------------------------------------
// K1: one block per (slice, modality, split). Streams 4096 contiguous sample
// rows' 32-dim window as float2, accumulating into an LDS per-class table via
// ds atomics (4-way bank aliasing, ~1.6x — cheap). Zero global atomics.
__global__ __launch_bounds__(TPB)
void trans_sum_kernel(const float2* __restrict__ m1,
                      const float2* __restrict__ m2,
                      const int* __restrict__ targets,
                      float* __restrict__ out) {
    int b     = blockIdx.x;
    int split = b & (S - 1);
    int mod   = (b >> 3) & 1;
    int slice = b >> 4;
    int t     = threadIdx.x;

    if (b == 0 && t == 0) out[0] = 0.0f;   // zeroed before loss kernel runs

    __shared__ alignas(16) float acc[NC * W];  // 50.5 KB
    __shared__ int tgt[CHUNK];                  // 16 KB
    __shared__ int lcnt[NC];

    for (int i = t; i < NC * W; i += TPB) acc[i] = 0.0f;
    bool counting = (slice == 0 && mod == 0);
    if (counting)
        for (int i = t; i < NC; i += TPB) lcnt[i] = 0;
    int base = split * CHUNK;
    for (int i = t; i < CHUNK; i += TPB) tgt[i] = targets[base + i];
    __syncthreads();
    if (counting)
        for (int i = t; i < CHUNK; i += TPB) atomicAdd(&lcnt[tgt[i]], 1);

    const float2* src = mod ? m2 : m1;
    int q   = t & 15;      // float2 slot within the 32-dim window
    int ls0 = t >> 4;      // starting local sample (0..31)
    const int soff = slice * 16 + q;   // float2 offset within a 256-float2 row

    // 32 samples/iteration-group, 4-deep unroll for outstanding loads.
    for (int ls = ls0; ls < CHUNK; ls += 32 * 4) {
        int s0 = ls, s1 = ls + 32, s2 = ls + 64, s3 = ls + 96;
        float2 v0 = src[(size_t)(base + s0) * 256 + soff];
        float2 v1 = src[(size_t)(base + s1) * 256 + soff];
        float2 v2 = src[(size_t)(base + s2) * 256 + soff];
        float2 v3 = src[(size_t)(base + s3) * 256 + soff];
        int c0 = tgt[s0], c1 = tgt[s1], c2 = tgt[s2], c3 = tgt[s3];
        atomicAdd(&acc[c0 * W + 2 * q],     v0.x);
        atomicAdd(&acc[c0 * W + 2 * q + 1], v0.y);
        atomicAdd(&acc[c1 * W + 2 * q],     v1.x);
        atomicAdd(&acc[c1 * W + 2 * q + 1], v1.y);
        atomicAdd(&acc[c2 * W + 2 * q],     v2.x);
        atomicAdd(&acc[c2 * W + 2 * q + 1], v2.y);
        atomicAdd(&acc[c3 * W + 2 * q],     v3.x);
        atomicAdd(&acc[c3 * W + 2 * q + 1], v3.y);
    }
    __syncthreads();

    // Epilogue: dump LDS accumulator to this block's private partial slab.
    float4* dst4 = reinterpret_cast<float4*>(&g_partial[(size_t)b * NC * W]);
    const float4* acc4 = reinterpret_cast<const float4*>(acc);
    for (int i = t; i < NC * W / 4; i += TPB) dst4[i] = acc4[i];
    if (counting)
        for (int i = t; i < NC; i += TPB) g_pcount[split * NC + i] = lcnt[i];
}

// ---------------------------------------------------------------------------
__device__ __forceinline__ float smooth_l1(float d) {
    d = fabsf(d);
    return d < 1.0f ? 0.5f * d * d : d - 0.5f;
}

// K2: combine partials + counts, SmoothL1 weighted by count, two-level reduce.
// Grid-stride with 256 blocks -> only 256 final atomics.
__global__ void loss_kernel(const float* __restrict__ centers,
                            float* __restrict__ out) {
    __shared__ float scnt[NC];
    int t = threadIdx.x;   // 256
    for (int c = t; c < NC; c += 256) {
        int s = 0;
        #pragma unroll
        for (int k = 0; k < S; k++) s += g_pcount[k * NC + c];
        scnt[c] = (float)s;
    }
    __syncthreads();

    float val = 0.0f;
    for (int gid = blockIdx.x * 256 + t; gid < NC * FD; gid += gridDim.x * 256) {
        int c = gid >> 9;          // FD == 512
        int d = gid & 511;
        int slice = d >> 5, dd = d & 31;
        float cnt = scnt[c];
        if (cnt > 0.0f) {
            float sum1 = 0.0f, sum2 = 0.0f;
            #pragma unroll
            for (int k = 0; k < S; k++) {
                sum1 += g_partial[(size_t)((slice << 4) | k)     * NC * W + c * W + dd];
                sum2 += g_partial[(size_t)((slice << 4) | 8 | k) * NC * W + c * W + dd];
            }
            float ctr = centers[gid];
            float inv = 1.0f / cnt;
            val += cnt * (smooth_l1(sum1 * inv - ctr) + smooth_l1(sum2 * inv - ctr));
        }
    }

    for (int off = 32; off > 0; off >>= 1)
        val += __shfl_down(val, off, 64);
    __shared__ float wsum[4];
    int lane = t & 63, wid = t >> 6;
    if (lane == 0) wsum[wid] = val;
    __syncthreads();
    if (t == 0) {
        float sm = wsum[0] + wsum[1] + wsum[2] + wsum[3];
        atomicAdd(out, sm * 5.9604644775390625e-08f);  // 1/(N*D) = 2^-24
    }
}

extern "C" void kernel_launch(void* const* d_in, const int* in_sizes, int n_in,
                              void* d_out, int out_size, void* d_ws, size_t ws_size,
                              hipStream_t stream) {
    const float2* m1 = (const float2*)d_in[0];
    const float2* m2 = (const float2*)d_in[1];
    const float* centers = (const float*)d_in[2];
    const int* targets = (const int*)d_in[3];
    float* out = (float*)d_out;

    trans_sum_kernel<<<NSLICE * 2 * S, TPB, 0, stream>>>(m1, m2, targets, out);
    loss_kernel<<<256, 256, 0, stream>>>(centers, out);
}

// Round 6
// 173.693 us; speedup vs baseline: 1.6633x; 1.6633x over previous
//
#include <hip/hip_runtime.h>

#define NS 32768
#define NC 395
#define FD 512
#define SPL 16
#define CHUNK (NS / SPL)   // 2048 targets scanned per block
#define TPB 256

// Static device scratch — every slot rewritten each call.
// g_partial[(split*2+mod)][class][dim]  (~25.9 MB)
__device__ float g_partial[SPL * 2 * NC * FD];
__device__ int   g_pcount[SPL * NC];

// ---------------------------------------------------------------------------
__device__ __forceinline__ void f4add(float4& a, const float4 b) {
    a.x += b.x; a.y += b.y; a.z += b.z; a.w += b.w;
}

// K1: one block per (class, split). Scan phase: 2 hoisted int4 loads/thread
// (one vmcnt round for the whole 2048-target chunk), compact matches into LDS
// with native int LDS atomics. Gather phase: threads 0-127 modality 1,
// 128-255 modality 2; register accumulation, zero global atomics.
__global__ __launch_bounds__(TPB)
void gather_sum_kernel(const float4* __restrict__ m1,
                       const float4* __restrict__ m2,
                       const int* __restrict__ targets,
                       float* __restrict__ out) {
    int c   = blockIdx.x >> 4;        // class
    int s   = blockIdx.x & (SPL - 1); // split
    int tid = threadIdx.x;

    if (blockIdx.x == 0 && tid == 0) out[0] = 0.0f;  // zero before loss kernel

    __shared__ int sidx[CHUNK];   // worst case: whole chunk one class (8 KB)
    __shared__ int scnt;
    if (tid == 0) scnt = 0;
    __syncthreads();

    int sbase = s * CHUNK;
    const int4* t4 = reinterpret_cast<const int4*>(targets + sbase);
    int4 ta = t4[tid];            // both loads issued back-to-back:
    int4 tb = t4[tid + TPB];      // single memory round-trip for the scan
    int i0 = sbase + 4 * tid;
    int i1 = sbase + 4 * (tid + TPB);
    if (ta.x == c) sidx[atomicAdd(&scnt, 1)] = i0;
    if (ta.y == c) sidx[atomicAdd(&scnt, 1)] = i0 + 1;
    if (ta.z == c) sidx[atomicAdd(&scnt, 1)] = i0 + 2;
    if (ta.w == c) sidx[atomicAdd(&scnt, 1)] = i0 + 3;
    if (tb.x == c) sidx[atomicAdd(&scnt, 1)] = i1;
    if (tb.y == c) sidx[atomicAdd(&scnt, 1)] = i1 + 1;
    if (tb.z == c) sidx[atomicAdd(&scnt, 1)] = i1 + 2;
    if (tb.w == c) sidx[atomicAdd(&scnt, 1)] = i1 + 3;
    __syncthreads();
    int cnt = scnt;

    int m = tid >> 7;             // modality (wave-uniform)
    int q = tid & 127;            // float4 quad within the 512-dim row
    const float4* src = m ? m2 : m1;

    float4 a0 = make_float4(0.f, 0.f, 0.f, 0.f);
    float4 a1 = a0, a2 = a0, a3 = a0;

    int j = 0;
    for (; j + 4 <= cnt; j += 4) {
        int s0 = sidx[j], s1 = sidx[j + 1], s2 = sidx[j + 2], s3 = sidx[j + 3];
        float4 v0 = src[(size_t)s0 * 128 + q];
        float4 v1 = src[(size_t)s1 * 128 + q];
        float4 v2 = src[(size_t)s2 * 128 + q];
        float4 v3 = src[(size_t)s3 * 128 + q];
        f4add(a0, v0); f4add(a1, v1); f4add(a2, v2); f4add(a3, v3);
    }
    for (; j < cnt; j++)
        f4add(a0, src[(size_t)sidx[j] * 128 + q]);
    f4add(a0, a1); f4add(a2, a3); f4add(a0, a2);

    // partial[(s*2+m)][c][q*4..] — always written (zeros if no matches).
    float4* dst = reinterpret_cast<float4*>(g_partial);
    dst[(((size_t)s * 2 + m) * NC + c) * 128 + q] = a0;
    if (tid == 0) g_pcount[s * NC + c] = cnt;
}

// ---------------------------------------------------------------------------
__device__ __forceinline__ float smooth_l1(float d) {
    d = fabsf(d);
    return d < 1.0f ? 0.5f * d * d : d - 0.5f;
}

// K2: combine partials + counts, SmoothL1 weighted by count, two-level reduce.
// 512 grid-stride blocks -> parallel 26 MB partial read, 512 final atomics.
__global__ void loss_kernel(const float* __restrict__ centers,
                            float* __restrict__ out) {
    __shared__ float scnt[NC];
    int t = threadIdx.x;   // 256
    for (int c = t; c < NC; c += 256) {
        int sc = 0;
        #pragma unroll
        for (int k = 0; k < SPL; k++) sc += g_pcount[k * NC + c];
        scnt[c] = (float)sc;
    }
    __syncthreads();

    float val = 0.0f;
    for (int gid = blockIdx.x * 256 + t; gid < NC * FD; gid += gridDim.x * 256) {
        int c = gid >> 9;          // FD == 512
        float cnt = scnt[c];
        if (cnt > 0.0f) {
            float sum1 = 0.0f, sum2 = 0.0f;
            #pragma unroll
            for (int k = 0; k < SPL; k++) {
                sum1 += g_partial[(size_t)(2 * k)     * NC * FD + gid];
                sum2 += g_partial[(size_t)(2 * k + 1) * NC * FD + gid];
            }
            float ctr = centers[gid];
            float inv = 1.0f / cnt;
            val += cnt * (smooth_l1(sum1 * inv - ctr) + smooth_l1(sum2 * inv - ctr));
        }
    }

    for (int off = 32; off > 0; off >>= 1)
        val += __shfl_down(val, off, 64);
    __shared__ float wsum[4];
    int lane = t & 63, wid = t >> 6;
    if (lane == 0) wsum[wid] = val;
    __syncthreads();
    if (t == 0) {
        float sm = wsum[0] + wsum[1] + wsum[2] + wsum[3];
        atomicAdd(out, sm * 5.9604644775390625e-08f);  // 1/(N*D) = 2^-24
    }
}

extern "C" void kernel_launch(void* const* d_in, const int* in_sizes, int n_in,
                              void* d_out, int out_size, void* d_ws, size_t ws_size,
                              hipStream_t stream) {
    const float4* m1 = (const float4*)d_in[0];
    const float4* m2 = (const float4*)d_in[1];
    const float* centers = (const float*)d_in[2];
    const int* targets = (const int*)d_in[3];
    float* out = (float*)d_out;

    gather_sum_kernel<<<NC * SPL, TPB, 0, stream>>>(m1, m2, targets, out);
    loss_kernel<<<512, 256, 0, stream>>>(centers, out);
}